// Round 1
// baseline (1657.776 us; speedup 1.0000x reference)
//
#include <hip/hip_runtime.h>
#include <hip/hip_bf16.h>

#define HDIM 96
#define TILE 128

typedef __attribute__((ext_vector_type(8))) short  short8;
typedef __attribute__((ext_vector_type(4))) float  float4v;
typedef __attribute__((ext_vector_type(4))) unsigned int uint4v;

static __device__ __forceinline__ short f2bf(float f){
    __hip_bfloat16 h = __float2bfloat16(f);
    return *reinterpret_cast<short*>(&h);
}
static __device__ __forceinline__ float silu_f(float v){
    return v / (1.0f + __expf(-v));
}

// ---------------- weight swizzle into MFMA B-fragment order ----------------
// dst frag layout: [kstep][ntile(6)][lane(64)][j(8)] ; element = W[k0+ (lane>>4)*8 + j][nt*16 + (lane&15)]
struct SwJob { const float* src; int ck; int ks; int ksrc; };
struct SwTable { SwJob j[22]; };

__global__ __launch_bounds__(256) void swizzle_kernel(SwTable T, short* __restrict__ dst, int total){
    int gid = blockIdx.x*256 + threadIdx.x;
    if (gid >= total) return;
    int ksg = gid / 3072;
    int e   = gid % 3072;
    const float* src = T.j[0].src; int k0 = 0, ksrc = 0;
    #pragma unroll
    for (int jj = 0; jj < 22; ++jj){
        int s = T.j[jj].ck;
        if (ksg >= s && ksg < s + T.j[jj].ks){ src = T.j[jj].src; k0 = (ksg - s)*32; ksrc = T.j[jj].ksrc; }
    }
    int nt   = e >> 9;
    int rem  = e & 511;
    int lane = rem >> 3;
    int jx   = rem & 7;
    int k = k0 + ((lane >> 4) << 3) + jx;
    int f = nt*16 + (lane & 15);
    float v = (k < ksrc) ? src[(size_t)k*HDIM + f] : 0.0f;
    dst[gid] = f2bf(v);
}

// ---------------- edge message + scatter-add ----------------
__global__ __launch_bounds__(256,2) void edge_kernel(
    const short* __restrict__ hbf, const int* __restrict__ send, const int* __restrict__ rec,
    const float* __restrict__ pos,
    const short* __restrict__ w1sw, const float* __restrict__ w1r192, const float* __restrict__ b1,
    const short* __restrict__ w2sw, const float* __restrict__ b2,
    float* __restrict__ aggr, int E)
{
    __shared__ short stateS[TILE*200];   // 128 rows x (192 data + 8 pad) bf16
    __shared__ float distS[TILE];
    __shared__ int   recS[TILE];
    const int t  = threadIdx.x;
    const int e0 = blockIdx.x * TILE;

    // stage h[send] | h[rec] rows into LDS (bf16, 16B chunks)
    #pragma unroll
    for (int it = 0; it < 12; ++it) {
        int q = it*256 + t;            // 128 edges * 2 parts * 12 chunks
        int c = q % 12;
        int rest = q / 12;
        int part = rest & 1;
        int i = rest >> 1;
        int e = e0 + i; if (e >= E) e = E - 1;
        int node = (part == 0) ? send[e] : rec[e];
        uint4v v = *(const uint4v*)(hbf + (size_t)node*HDIM + c*8);
        *(uint4v*)(stateS + i*200 + part*HDIM + c*8) = v;
    }
    if (t < TILE) {
        int e = e0 + t; if (e >= E) e = E - 1;
        int s = send[e], r = rec[e];
        recS[t] = r;
        float dx = pos[3*s]   - pos[3*r];
        float dy = pos[3*s+1] - pos[3*r+1];
        float dz = pos[3*s+2] - pos[3*r+2];
        distS[t] = sqrtf(dx*dx + dy*dy + dz*dz);
    }
    __syncthreads();

    const int lane = t & 63;
    const int wv   = t >> 6;
    const int m0   = wv * 32;
    const int arow = lane & 15;
    const int aq   = lane >> 4;
    const int aoff = aq * 8;
    const int crow = aq * 4;
    const float4v fzero = {0.f,0.f,0.f,0.f};

    float4v acc[2][6];
    #pragma unroll
    for (int i=0;i<2;i++)
      #pragma unroll
      for (int n=0;n<6;n++) acc[i][n] = fzero;

    const short8* w1f = (const short8*)w1sw;
    #pragma unroll
    for (int ks = 0; ks < 6; ++ks) {
        short8 a0 = *(const short8*)(stateS + (m0+arow)*200    + ks*32 + aoff);
        short8 a1 = *(const short8*)(stateS + (m0+16+arow)*200 + ks*32 + aoff);
        #pragma unroll
        for (int nt = 0; nt < 6; ++nt) {
            short8 b = w1f[(ks*6+nt)*64 + lane];
            acc[0][nt] = __builtin_amdgcn_mfma_f32_16x16x32_bf16(a0, b, acc[0][nt], 0, 0, 0);
            acc[1][nt] = __builtin_amdgcn_mfma_f32_16x16x32_bf16(a1, b, acc[1][nt], 0, 0, 0);
        }
    }
    __syncthreads();    // all waves done reading stateS before t1 overwrites it

    short* t1S = stateS;   // alias, stride 104
    #pragma unroll
    for (int i=0;i<2;i++)
      #pragma unroll
      for (int nt=0;nt<6;nt++){
        int f = nt*16 + arow;
        float w1d = w1r192[f];
        float bb  = b1[f];
        #pragma unroll
        for (int r=0;r<4;r++){
            int m = m0 + i*16 + crow + r;
            float v = acc[i][nt][r] + distS[m]*w1d + bb;
            t1S[m*104 + f] = f2bf(silu_f(v));
        }
      }
    __syncthreads();

    #pragma unroll
    for (int i=0;i<2;i++)
      #pragma unroll
      for (int n=0;n<6;n++) acc[i][n] = fzero;

    const short8* w2f = (const short8*)w2sw;
    #pragma unroll
    for (int ks = 0; ks < 3; ++ks) {
        short8 a0 = *(const short8*)(t1S + (m0+arow)*104    + ks*32 + aoff);
        short8 a1 = *(const short8*)(t1S + (m0+16+arow)*104 + ks*32 + aoff);
        #pragma unroll
        for (int nt = 0; nt < 6; ++nt) {
            short8 b = w2f[(ks*6+nt)*64 + lane];
            acc[0][nt] = __builtin_amdgcn_mfma_f32_16x16x32_bf16(a0, b, acc[0][nt], 0, 0, 0);
            acc[1][nt] = __builtin_amdgcn_mfma_f32_16x16x32_bf16(a1, b, acc[1][nt], 0, 0, 0);
        }
    }

    #pragma unroll
    for (int i=0;i<2;i++)
      #pragma unroll
      for (int nt=0;nt<6;nt++){
        int f = nt*16 + arow;
        float bb = b2[f];
        #pragma unroll
        for (int r=0;r<4;r++){
            int m = m0 + i*16 + crow + r;
            if (e0 + m < E) {
                float v = silu_f(acc[i][nt][r] + bb);
                atomicAdd(&aggr[(size_t)recS[m]*HDIM + f], v);
            }
        }
      }
}

// ---------------- node update: h += MLP([h, aggr]); re-zero aggr ----------------
__global__ __launch_bounds__(256,2) void update_kernel(
    float* __restrict__ h, short* __restrict__ hbf, float* __restrict__ aggr,
    const short* __restrict__ w1sw, const float* __restrict__ b1,
    const short* __restrict__ w2sw, const float* __restrict__ b2, int N)
{
    __shared__ short stateS[TILE*200];
    const int t  = threadIdx.x;
    const int n0 = blockIdx.x * TILE;

    #pragma unroll
    for (int it = 0; it < 12; ++it) {
        int q = it*256 + t;    // 128 rows * 24 chunks
        int c = q % 24;
        int i = q / 24;
        int node = n0 + i;
        if (c < 12) {
            uint4v v = {0u,0u,0u,0u};
            if (node < N) v = *(const uint4v*)(hbf + (size_t)node*HDIM + c*8);
            *(uint4v*)(stateS + i*200 + c*8) = v;
        } else {
            int cc = c - 12;
            short8 s8 = {0,0,0,0,0,0,0,0};
            if (node < N) {
                float4v a0 = *(const float4v*)(aggr + (size_t)node*HDIM + cc*8);
                float4v a1 = *(const float4v*)(aggr + (size_t)node*HDIM + cc*8 + 4);
                s8[0]=f2bf(a0[0]); s8[1]=f2bf(a0[1]); s8[2]=f2bf(a0[2]); s8[3]=f2bf(a0[3]);
                s8[4]=f2bf(a1[0]); s8[5]=f2bf(a1[1]); s8[6]=f2bf(a1[2]); s8[7]=f2bf(a1[3]);
            }
            *(short8*)(stateS + i*200 + HDIM + cc*8) = s8;
        }
    }
    __syncthreads();

    const int lane = t & 63;
    const int wv   = t >> 6;
    const int m0   = wv * 32;
    const int arow = lane & 15;
    const int aq   = lane >> 4;
    const int aoff = aq * 8;
    const int crow = aq * 4;
    const float4v fzero = {0.f,0.f,0.f,0.f};

    float4v acc[2][6];
    #pragma unroll
    for (int i=0;i<2;i++)
      #pragma unroll
      for (int n=0;n<6;n++) acc[i][n] = fzero;

    const short8* w1f = (const short8*)w1sw;
    #pragma unroll
    for (int ks = 0; ks < 6; ++ks) {
        short8 a0 = *(const short8*)(stateS + (m0+arow)*200    + ks*32 + aoff);
        short8 a1 = *(const short8*)(stateS + (m0+16+arow)*200 + ks*32 + aoff);
        #pragma unroll
        for (int nt = 0; nt < 6; ++nt) {
            short8 b = w1f[(ks*6+nt)*64 + lane];
            acc[0][nt] = __builtin_amdgcn_mfma_f32_16x16x32_bf16(a0, b, acc[0][nt], 0, 0, 0);
            acc[1][nt] = __builtin_amdgcn_mfma_f32_16x16x32_bf16(a1, b, acc[1][nt], 0, 0, 0);
        }
    }
    __syncthreads();

    short* t1S = stateS;
    #pragma unroll
    for (int i=0;i<2;i++)
      #pragma unroll
      for (int nt=0;nt<6;nt++){
        int f = nt*16 + arow;
        float bb = b1[f];
        #pragma unroll
        for (int r=0;r<4;r++){
            int m = m0 + i*16 + crow + r;
            t1S[m*104 + f] = f2bf(silu_f(acc[i][nt][r] + bb));
        }
      }
    __syncthreads();

    #pragma unroll
    for (int i=0;i<2;i++)
      #pragma unroll
      for (int n=0;n<6;n++) acc[i][n] = fzero;

    const short8* w2f = (const short8*)w2sw;
    #pragma unroll
    for (int ks = 0; ks < 3; ++ks) {
        short8 a0 = *(const short8*)(t1S + (m0+arow)*104    + ks*32 + aoff);
        short8 a1 = *(const short8*)(t1S + (m0+16+arow)*104 + ks*32 + aoff);
        #pragma unroll
        for (int nt = 0; nt < 6; ++nt) {
            short8 b = w2f[(ks*6+nt)*64 + lane];
            acc[0][nt] = __builtin_amdgcn_mfma_f32_16x16x32_bf16(a0, b, acc[0][nt], 0, 0, 0);
            acc[1][nt] = __builtin_amdgcn_mfma_f32_16x16x32_bf16(a1, b, acc[1][nt], 0, 0, 0);
        }
    }

    #pragma unroll
    for (int i=0;i<2;i++)
      #pragma unroll
      for (int nt=0;nt<6;nt++){
        int f = nt*16 + arow;
        float bb = b2[f];
        #pragma unroll
        for (int r=0;r<4;r++){
            int m = m0 + i*16 + crow + r;
            int node = n0 + m;
            if (node < N) {
                size_t idx = (size_t)node*HDIM + f;
                float o = h[idx] + acc[i][nt][r] + bb;
                h[idx]   = o;
                hbf[idx] = f2bf(o);
                aggr[idx] = 0.0f;
            }
        }
      }
}

// ---------------- embed: h = silu([x|pe] W1 + b1) W2 + b2 ----------------
__global__ __launch_bounds__(256,2) void embed_kernel(
    const float* __restrict__ x, const float* __restrict__ pe,
    const short* __restrict__ w1sw, const float* __restrict__ b1,
    const short* __restrict__ w2sw, const float* __restrict__ b2,
    float* __restrict__ h, short* __restrict__ hbf, int N)
{
    __shared__ short stateS[TILE*72];    // K padded to 64, stride 72
    __shared__ short t1S[TILE*104];
    const int t  = threadIdx.x;
    const int n0 = blockIdx.x * TILE;

    if (t < TILE) {
        int node = n0 + t;
        short* row = stateS + t*72;
        if (node < N) {
            #pragma unroll
            for (int j=0;j<11;j++) row[j]    = f2bf(x[(size_t)node*11 + j]);
            #pragma unroll
            for (int j=0;j<24;j++) row[11+j] = f2bf(pe[(size_t)node*24 + j]);
            #pragma unroll
            for (int j=35;j<64;j++) row[j] = 0;
        } else {
            #pragma unroll
            for (int j=0;j<64;j++) row[j] = 0;
        }
    }
    __syncthreads();

    const int lane = t & 63;
    const int wv   = t >> 6;
    const int m0   = wv * 32;
    const int arow = lane & 15;
    const int aq   = lane >> 4;
    const int aoff = aq * 8;
    const int crow = aq * 4;
    const float4v fzero = {0.f,0.f,0.f,0.f};

    float4v acc[2][6];
    #pragma unroll
    for (int i=0;i<2;i++)
      #pragma unroll
      for (int n=0;n<6;n++) acc[i][n] = fzero;

    const short8* w1f = (const short8*)w1sw;
    #pragma unroll
    for (int ks = 0; ks < 2; ++ks) {
        short8 a0 = *(const short8*)(stateS + (m0+arow)*72    + ks*32 + aoff);
        short8 a1 = *(const short8*)(stateS + (m0+16+arow)*72 + ks*32 + aoff);
        #pragma unroll
        for (int nt = 0; nt < 6; ++nt) {
            short8 b = w1f[(ks*6+nt)*64 + lane];
            acc[0][nt] = __builtin_amdgcn_mfma_f32_16x16x32_bf16(a0, b, acc[0][nt], 0, 0, 0);
            acc[1][nt] = __builtin_amdgcn_mfma_f32_16x16x32_bf16(a1, b, acc[1][nt], 0, 0, 0);
        }
    }

    #pragma unroll
    for (int i=0;i<2;i++)
      #pragma unroll
      for (int nt=0;nt<6;nt++){
        int f = nt*16 + arow;
        float bb = b1[f];
        #pragma unroll
        for (int r=0;r<4;r++){
            int m = m0 + i*16 + crow + r;
            t1S[m*104 + f] = f2bf(silu_f(acc[i][nt][r] + bb));
        }
      }
    __syncthreads();

    #pragma unroll
    for (int i=0;i<2;i++)
      #pragma unroll
      for (int n=0;n<6;n++) acc[i][n] = fzero;

    const short8* w2f = (const short8*)w2sw;
    #pragma unroll
    for (int ks = 0; ks < 3; ++ks) {
        short8 a0 = *(const short8*)(t1S + (m0+arow)*104    + ks*32 + aoff);
        short8 a1 = *(const short8*)(t1S + (m0+16+arow)*104 + ks*32 + aoff);
        #pragma unroll
        for (int nt = 0; nt < 6; ++nt) {
            short8 b = w2f[(ks*6+nt)*64 + lane];
            acc[0][nt] = __builtin_amdgcn_mfma_f32_16x16x32_bf16(a0, b, acc[0][nt], 0, 0, 0);
            acc[1][nt] = __builtin_amdgcn_mfma_f32_16x16x32_bf16(a1, b, acc[1][nt], 0, 0, 0);
        }
    }

    #pragma unroll
    for (int i=0;i<2;i++)
      #pragma unroll
      for (int nt=0;nt<6;nt++){
        int f = nt*16 + arow;
        float bb = b2[f];
        #pragma unroll
        for (int r=0;r<4;r++){
            int m = m0 + i*16 + crow + r;
            int node = n0 + m;
            if (node < N) {
                size_t idx = (size_t)node*HDIM + f;
                float o = acc[i][nt][r] + bb;
                h[idx]   = o;
                hbf[idx] = f2bf(o);
            }
        }
      }
}

// ---------------- pre-MLP fused with graph pooling ----------------
__global__ __launch_bounds__(256,2) void prepool_kernel(
    const short* __restrict__ hbf,
    const short* __restrict__ w1sw, const float* __restrict__ b1,
    const short* __restrict__ w2sw, const float* __restrict__ b2,
    const int* __restrict__ batch, float* __restrict__ pooled, int N)
{
    __shared__ short stateS[TILE*104];
    __shared__ short t1S[TILE*104];
    const int t  = threadIdx.x;
    const int n0 = blockIdx.x * TILE;

    #pragma unroll
    for (int it = 0; it < 6; ++it) {
        int q = it*256 + t;    // 128 rows * 12 chunks
        int c = q % 12;
        int i = q / 12;
        int node = n0 + i;
        uint4v v = {0u,0u,0u,0u};
        if (node < N) v = *(const uint4v*)(hbf + (size_t)node*HDIM + c*8);
        *(uint4v*)(stateS + i*104 + c*8) = v;
    }
    __syncthreads();

    const int lane = t & 63;
    const int wv   = t >> 6;
    const int m0   = wv * 32;
    const int arow = lane & 15;
    const int aq   = lane >> 4;
    const int aoff = aq * 8;
    const int crow = aq * 4;
    const float4v fzero = {0.f,0.f,0.f,0.f};

    float4v acc[2][6];
    #pragma unroll
    for (int i=0;i<2;i++)
      #pragma unroll
      for (int n=0;n<6;n++) acc[i][n] = fzero;

    const short8* w1f = (const short8*)w1sw;
    #pragma unroll
    for (int ks = 0; ks < 3; ++ks) {
        short8 a0 = *(const short8*)(stateS + (m0+arow)*104    + ks*32 + aoff);
        short8 a1 = *(const short8*)(stateS + (m0+16+arow)*104 + ks*32 + aoff);
        #pragma unroll
        for (int nt = 0; nt < 6; ++nt) {
            short8 b = w1f[(ks*6+nt)*64 + lane];
            acc[0][nt] = __builtin_amdgcn_mfma_f32_16x16x32_bf16(a0, b, acc[0][nt], 0, 0, 0);
            acc[1][nt] = __builtin_amdgcn_mfma_f32_16x16x32_bf16(a1, b, acc[1][nt], 0, 0, 0);
        }
    }

    #pragma unroll
    for (int i=0;i<2;i++)
      #pragma unroll
      for (int nt=0;nt<6;nt++){
        int f = nt*16 + arow;
        float bb = b1[f];
        #pragma unroll
        for (int r=0;r<4;r++){
            int m = m0 + i*16 + crow + r;
            t1S[m*104 + f] = f2bf(silu_f(acc[i][nt][r] + bb));
        }
      }
    __syncthreads();

    #pragma unroll
    for (int i=0;i<2;i++)
      #pragma unroll
      for (int n=0;n<6;n++) acc[i][n] = fzero;

    const short8* w2f = (const short8*)w2sw;
    #pragma unroll
    for (int ks = 0; ks < 3; ++ks) {
        short8 a0 = *(const short8*)(t1S + (m0+arow)*104    + ks*32 + aoff);
        short8 a1 = *(const short8*)(t1S + (m0+16+arow)*104 + ks*32 + aoff);
        #pragma unroll
        for (int nt = 0; nt < 6; ++nt) {
            short8 b = w2f[(ks*6+nt)*64 + lane];
            acc[0][nt] = __builtin_amdgcn_mfma_f32_16x16x32_bf16(a0, b, acc[0][nt], 0, 0, 0);
            acc[1][nt] = __builtin_amdgcn_mfma_f32_16x16x32_bf16(a1, b, acc[1][nt], 0, 0, 0);
        }
    }

    #pragma unroll
    for (int i=0;i<2;i++)
      #pragma unroll
      for (int nt=0;nt<6;nt++){
        int f = nt*16 + arow;
        float bb = b2[f];
        #pragma unroll
        for (int r=0;r<4;r++){
            int m = m0 + i*16 + crow + r;
            int node = n0 + m;
            if (node < N) {
                float v = acc[i][nt][r] + bb;
                atomicAdd(&pooled[(size_t)batch[node]*HDIM + f], v);
            }
        }
      }
}

// ---------------- readout: out[g] = silu(pooled W1 + b1) W2 + b2 ----------------
__global__ __launch_bounds__(128) void readout_kernel(
    const float* __restrict__ pooled,
    const float* __restrict__ w1, const float* __restrict__ b1,
    const float* __restrict__ w2, const float* __restrict__ b2,
    float* __restrict__ out)
{
    __shared__ float red[128];
    const int g = blockIdx.x;
    const int t = threadIdx.x;
    float p = 0.0f;
    if (t < HDIM) {
        float acc = b1[t];
        for (int k = 0; k < HDIM; ++k)
            acc += pooled[(size_t)g*HDIM + k] * w1[(size_t)k*HDIM + t];
        acc = silu_f(acc);
        p = acc * w2[t];
    }
    red[t] = p;
    __syncthreads();
    for (int s = 64; s > 0; s >>= 1) {
        if (t < s) red[t] += red[t + s];
        __syncthreads();
    }
    if (t == 0) out[g] = red[0] + b2[0];
}

extern "C" void kernel_launch(void* const* d_in, const int* in_sizes, int n_in,
                              void* d_out, int out_size, void* d_ws, size_t ws_size,
                              hipStream_t stream)
{
    const float* x        = (const float*)d_in[0];
    const float* pos      = (const float*)d_in[1];
    const float* pe       = (const float*)d_in[2];
    const int*   ei       = (const int*)d_in[3];
    const int*   batch    = (const int*)d_in[4];
    const float* embed_w1 = (const float*)d_in[5];
    const float* embed_b1 = (const float*)d_in[6];
    const float* embed_w2 = (const float*)d_in[7];
    const float* embed_b2 = (const float*)d_in[8];
    const float* msg_w1   = (const float*)d_in[9];
    const float* msg_b1   = (const float*)d_in[10];
    const float* msg_w2   = (const float*)d_in[11];
    const float* msg_b2   = (const float*)d_in[12];
    const float* upd_w1   = (const float*)d_in[13];
    const float* upd_b1   = (const float*)d_in[14];
    const float* upd_w2   = (const float*)d_in[15];
    const float* upd_b2   = (const float*)d_in[16];
    const float* pre_w1   = (const float*)d_in[17];
    const float* pre_b1   = (const float*)d_in[18];
    const float* pre_w2   = (const float*)d_in[19];
    const float* pre_b2   = (const float*)d_in[20];
    const float* ro_w1    = (const float*)d_in[21];
    const float* ro_b1    = (const float*)d_in[22];
    const float* ro_w2    = (const float*)d_in[23];
    const float* ro_b2    = (const float*)d_in[24];

    const int E = in_sizes[3] / 2;
    const int N = in_sizes[4];
    const int G = out_size;

    char* ws = (char*)d_ws;
    size_t off = 0;
    float* h      = (float*)(ws + off); off += (size_t)N*HDIM*4;
    short* hbf    = (short*)(ws + off); off += (size_t)N*HDIM*2;
    float* aggr   = (float*)(ws + off); off += (size_t)N*HDIM*4;
    float* pooled = (float*)(ws + off); off += (size_t)G*HDIM*4;
    short* wsw    = (short*)(ws + off); off += (size_t)83*3072*2;

    hipMemsetAsync(aggr,   0, (size_t)N*HDIM*4, stream);
    hipMemsetAsync(pooled, 0, (size_t)G*HDIM*4, stream);

    SwTable T;
    int ck = 0, ji = 0;
    auto add = [&](const float* s, int ks, int ksrc){
        T.j[ji].src = s; T.j[ji].ck = ck; T.j[ji].ks = ks; T.j[ji].ksrc = ksrc;
        ji++; ck += ks;
    };
    add(embed_w1, 2, 35);   // ck 0
    add(embed_w2, 3, 96);   // ck 2
    add(pre_w1,   3, 96);   // ck 5
    add(pre_w2,   3, 96);   // ck 8
    for (int l=0;l<4;l++) add(msg_w1 + (size_t)l*193*96, 6, 192);  // ck 11+6l
    for (int l=0;l<4;l++) add(msg_w2 + (size_t)l*96*96,  3, 96);   // ck 35+3l
    for (int l=0;l<4;l++) add(upd_w1 + (size_t)l*192*96, 6, 192);  // ck 47+6l
    for (int l=0;l<4;l++) add(upd_w2 + (size_t)l*96*96,  3, 96);   // ck 71+3l
    const int total = 83*3072;
    swizzle_kernel<<<(total+255)/256, 256, 0, stream>>>(T, wsw, total);

    const int nbN = (N + TILE - 1) / TILE;
    embed_kernel<<<nbN, 256, 0, stream>>>(x, pe, wsw + 0, embed_b1, wsw + 2*3072, embed_b2, h, hbf, N);

    const int nbE = (E + TILE - 1) / TILE;
    for (int l = 0; l < 4; ++l) {
        edge_kernel<<<nbE, 256, 0, stream>>>(hbf, ei, ei + E, pos,
            wsw + (11 + 6*l)*3072, msg_w1 + (size_t)l*193*96 + (size_t)192*96, msg_b1 + l*96,
            wsw + (35 + 3*l)*3072, msg_b2 + l*96, aggr, E);
        update_kernel<<<nbN, 256, 0, stream>>>(h, hbf, aggr,
            wsw + (47 + 6*l)*3072, upd_b1 + l*96,
            wsw + (71 + 3*l)*3072, upd_b2 + l*96, N);
    }

    prepool_kernel<<<nbN, 256, 0, stream>>>(hbf, wsw + 5*3072, pre_b1, wsw + 8*3072, pre_b2,
                                            batch, pooled, N);
    readout_kernel<<<G, 128, 0, stream>>>(pooled, ro_w1, ro_b1, ro_w2, ro_b2, (float*)d_out);
}

// Round 2
// 1112.830 us; speedup vs baseline: 1.4897x; 1.4897x over previous
//
#include <hip/hip_runtime.h>
#include <hip/hip_bf16.h>

#define HDIM 96
#define TILE 128

typedef __attribute__((ext_vector_type(8))) short  short8;
typedef __attribute__((ext_vector_type(4))) float  float4v;
typedef __attribute__((ext_vector_type(4))) unsigned int uint4v;

static __device__ __forceinline__ short f2bf(float f){
    __hip_bfloat16 h = __float2bfloat16(f);
    return *reinterpret_cast<short*>(&h);
}
static __device__ __forceinline__ float silu_f(float v){
    return v / (1.0f + __expf(-v));
}

// ---------------- weight swizzle into MFMA B-fragment order ----------------
struct SwJob { const float* src; int ck; int ks; int ksrc; };
struct SwTable { SwJob j[22]; };

__global__ __launch_bounds__(256) void swizzle_kernel(SwTable T, short* __restrict__ dst, int total){
    int gid = blockIdx.x*256 + threadIdx.x;
    if (gid >= total) return;
    int ksg = gid / 3072;
    int e   = gid % 3072;
    const float* src = T.j[0].src; int k0 = 0, ksrc = 0;
    #pragma unroll
    for (int jj = 0; jj < 22; ++jj){
        int s = T.j[jj].ck;
        if (ksg >= s && ksg < s + T.j[jj].ks){ src = T.j[jj].src; k0 = (ksg - s)*32; ksrc = T.j[jj].ksrc; }
    }
    int nt   = e >> 9;
    int rem  = e & 511;
    int lane = rem >> 3;
    int jx   = rem & 7;
    int k = k0 + ((lane >> 4) << 3) + jx;
    int f = nt*16 + (lane & 15);
    float v = (k < ksrc) ? src[(size_t)k*HDIM + f] : 0.0f;
    dst[gid] = f2bf(v);
}

// ---------------- edge sorting (counting sort by rec) ----------------
__global__ __launch_bounds__(256) void hist_kernel(const int* __restrict__ rec, int* __restrict__ deg, int E){
    int e = blockIdx.x*256 + threadIdx.x;
    if (e < E) atomicAdd(&deg[rec[e]], 1);
}

__global__ __launch_bounds__(1024) void scan_kernel(const int* __restrict__ deg, int* __restrict__ cur, int n){
    __shared__ int buf[1024];
    __shared__ int carry;
    const int t = threadIdx.x;
    if (t == 0) carry = 0;
    __syncthreads();
    for (int base = 0; base < n; base += 1024){
        int v = (base + t < n) ? deg[base + t] : 0;
        buf[t] = v;
        __syncthreads();
        #pragma unroll
        for (int off = 1; off < 1024; off <<= 1){
            int u = (t >= off) ? buf[t - off] : 0;
            __syncthreads();
            buf[t] += u;
            __syncthreads();
        }
        if (base + t < n) cur[base + t] = buf[t] - v + carry;
        __syncthreads();
        if (t == 0) carry += buf[1023];
        __syncthreads();
    }
}

__global__ __launch_bounds__(256) void scatter_kernel(
    const int* __restrict__ send, const int* __restrict__ rec, const float* __restrict__ pos,
    int* __restrict__ cur, int* __restrict__ send_s, int* __restrict__ rec_s,
    float* __restrict__ dist_s, int E)
{
    int e = blockIdx.x*256 + threadIdx.x;
    if (e >= E) return;
    int s = send[e], r = rec[e];
    int p = atomicAdd(&cur[r], 1);
    send_s[p] = s;
    rec_s[p]  = r;
    float dx = pos[3*s]   - pos[3*r];
    float dy = pos[3*s+1] - pos[3*r+1];
    float dz = pos[3*s+2] - pos[3*r+2];
    dist_s[p] = sqrtf(dx*dx + dy*dy + dz*dz);
}

// ---------------- edge message + segment-reduced scatter-add ----------------
__global__ __launch_bounds__(256,3) void edge_kernel(
    const short* __restrict__ hbf,
    const int* __restrict__ send_s, const int* __restrict__ rec_s, const float* __restrict__ dist_s,
    const short* __restrict__ w1sw, const float* __restrict__ w1r192, const float* __restrict__ b1,
    const short* __restrict__ w2sw, const float* __restrict__ b2,
    float* __restrict__ aggr, int E)
{
    __shared__ short stateS[TILE*200];   // 51200 B; later aliased as msgS (128 x 100 fp32)
    __shared__ float distS[TILE];
    __shared__ int   recS[TILE];
    __shared__ int   segIdxS[TILE];
    __shared__ int   startIdxS[TILE+1];
    const int t  = threadIdx.x;
    const int e0 = blockIdx.x * TILE;

    // stage h[send] | h[rec] rows into LDS (bf16, 16B chunks); edges sorted by rec
    #pragma unroll
    for (int it = 0; it < 12; ++it) {
        int q = it*256 + t;            // 128 edges * 2 parts * 12 chunks
        int c = q % 12;
        int rest = q / 12;
        int part = rest & 1;
        int i = rest >> 1;
        int e = e0 + i; if (e >= E) e = E - 1;
        int node = (part == 0) ? send_s[e] : rec_s[e];
        uint4v v = *(const uint4v*)(hbf + (size_t)node*HDIM + c*8);
        *(uint4v*)(stateS + i*200 + part*HDIM + c*8) = v;
    }
    if (t < TILE) {
        int e = e0 + t; if (e >= E) e = E - 1;
        recS[t]  = rec_s[e];
        distS[t] = dist_s[e];
    }
    __syncthreads();

    // build segment table over the (sorted) rec values of this tile
    if (t < TILE) segIdxS[t] = (t == 0) || (recS[t] != recS[t-1]);
    __syncthreads();
    #pragma unroll
    for (int off = 1; off < TILE; off <<= 1){
        int u = 0;
        if (t < TILE && t >= off) u = segIdxS[t - off];
        __syncthreads();
        if (t < TILE) segIdxS[t] += u;
        __syncthreads();
    }
    if (t < TILE && ((t == 0) || (recS[t] != recS[t-1]))) startIdxS[segIdxS[t]-1] = t;
    __syncthreads();
    const int nseg = segIdxS[TILE-1];
    if (t == 0) startIdxS[nseg] = TILE;
    __syncthreads();

    const int lane = t & 63;
    const int wv   = t >> 6;
    const int m0   = wv * 32;
    const int arow = lane & 15;
    const int aq   = lane >> 4;
    const int aoff = aq * 8;
    const int crow = aq * 4;
    const float4v fzero = {0.f,0.f,0.f,0.f};

    float4v acc[2][6];
    #pragma unroll
    for (int i=0;i<2;i++)
      #pragma unroll
      for (int n=0;n<6;n++) acc[i][n] = fzero;

    const short8* w1f = (const short8*)w1sw;
    #pragma unroll
    for (int ks = 0; ks < 6; ++ks) {
        short8 a0 = *(const short8*)(stateS + (m0+arow)*200    + ks*32 + aoff);
        short8 a1 = *(const short8*)(stateS + (m0+16+arow)*200 + ks*32 + aoff);
        #pragma unroll
        for (int nt = 0; nt < 6; ++nt) {
            short8 b = w1f[(ks*6+nt)*64 + lane];
            acc[0][nt] = __builtin_amdgcn_mfma_f32_16x16x32_bf16(a0, b, acc[0][nt], 0, 0, 0);
            acc[1][nt] = __builtin_amdgcn_mfma_f32_16x16x32_bf16(a1, b, acc[1][nt], 0, 0, 0);
        }
    }
    __syncthreads();    // all waves done reading stateS before t1 overwrites it

    short* t1S = stateS;   // alias, stride 104
    #pragma unroll
    for (int i=0;i<2;i++)
      #pragma unroll
      for (int nt=0;nt<6;nt++){
        int f = nt*16 + arow;
        float w1d = w1r192[f];
        float bb  = b1[f];
        #pragma unroll
        for (int r=0;r<4;r++){
            int m = m0 + i*16 + crow + r;
            float v = acc[i][nt][r] + distS[m]*w1d + bb;
            t1S[m*104 + f] = f2bf(silu_f(v));
        }
      }
    __syncthreads();

    #pragma unroll
    for (int i=0;i<2;i++)
      #pragma unroll
      for (int n=0;n<6;n++) acc[i][n] = fzero;

    const short8* w2f = (const short8*)w2sw;
    #pragma unroll
    for (int ks = 0; ks < 3; ++ks) {
        short8 a0 = *(const short8*)(t1S + (m0+arow)*104    + ks*32 + aoff);
        short8 a1 = *(const short8*)(t1S + (m0+16+arow)*104 + ks*32 + aoff);
        #pragma unroll
        for (int nt = 0; nt < 6; ++nt) {
            short8 b = w2f[(ks*6+nt)*64 + lane];
            acc[0][nt] = __builtin_amdgcn_mfma_f32_16x16x32_bf16(a0, b, acc[0][nt], 0, 0, 0);
            acc[1][nt] = __builtin_amdgcn_mfma_f32_16x16x32_bf16(a1, b, acc[1][nt], 0, 0, 0);
        }
    }
    __syncthreads();    // done reading t1S; msgS will overwrite it

    // write silu'd messages (fp32) into LDS, stride 100 floats
    float* msgS = (float*)stateS;
    #pragma unroll
    for (int i=0;i<2;i++)
      #pragma unroll
      for (int nt=0;nt<6;nt++){
        int f = nt*16 + arow;
        float bb = b2[f];
        #pragma unroll
        for (int r=0;r<4;r++){
            int m = m0 + i*16 + crow + r;
            float v = silu_f(acc[i][nt][r] + bb);
            if (e0 + m >= E) v = 0.0f;
            msgS[m*100 + f] = v;
        }
      }
    __syncthreads();

    // segment-sum per (segment, col), one atomic per output
    for (int item = t; item < nseg*HDIM; item += 256){
        int s = item / HDIM;
        int f = item - s*HDIM;
        int r0 = startIdxS[s], r1 = startIdxS[s+1];
        float sum = 0.0f;
        for (int r = r0; r < r1; ++r) sum += msgS[r*100 + f];
        atomicAdd(&aggr[(size_t)recS[r0]*HDIM + f], sum);
    }
}

// ---------------- node update: h += MLP([h, aggr]); re-zero aggr ----------------
__global__ __launch_bounds__(256,2) void update_kernel(
    float* __restrict__ h, short* __restrict__ hbf, float* __restrict__ aggr,
    const short* __restrict__ w1sw, const float* __restrict__ b1,
    const short* __restrict__ w2sw, const float* __restrict__ b2, int N)
{
    __shared__ short stateS[TILE*200];
    const int t  = threadIdx.x;
    const int n0 = blockIdx.x * TILE;

    #pragma unroll
    for (int it = 0; it < 12; ++it) {
        int q = it*256 + t;    // 128 rows * 24 chunks
        int c = q % 24;
        int i = q / 24;
        int node = n0 + i;
        if (c < 12) {
            uint4v v = {0u,0u,0u,0u};
            if (node < N) v = *(const uint4v*)(hbf + (size_t)node*HDIM + c*8);
            *(uint4v*)(stateS + i*200 + c*8) = v;
        } else {
            int cc = c - 12;
            short8 s8 = {0,0,0,0,0,0,0,0};
            if (node < N) {
                float4v a0 = *(const float4v*)(aggr + (size_t)node*HDIM + cc*8);
                float4v a1 = *(const float4v*)(aggr + (size_t)node*HDIM + cc*8 + 4);
                s8[0]=f2bf(a0[0]); s8[1]=f2bf(a0[1]); s8[2]=f2bf(a0[2]); s8[3]=f2bf(a0[3]);
                s8[4]=f2bf(a1[0]); s8[5]=f2bf(a1[1]); s8[6]=f2bf(a1[2]); s8[7]=f2bf(a1[3]);
            }
            *(short8*)(stateS + i*200 + HDIM + cc*8) = s8;
        }
    }
    __syncthreads();

    const int lane = t & 63;
    const int wv   = t >> 6;
    const int m0   = wv * 32;
    const int arow = lane & 15;
    const int aq   = lane >> 4;
    const int aoff = aq * 8;
    const int crow = aq * 4;
    const float4v fzero = {0.f,0.f,0.f,0.f};

    float4v acc[2][6];
    #pragma unroll
    for (int i=0;i<2;i++)
      #pragma unroll
      for (int n=0;n<6;n++) acc[i][n] = fzero;

    const short8* w1f = (const short8*)w1sw;
    #pragma unroll
    for (int ks = 0; ks < 6; ++ks) {
        short8 a0 = *(const short8*)(stateS + (m0+arow)*200    + ks*32 + aoff);
        short8 a1 = *(const short8*)(stateS + (m0+16+arow)*200 + ks*32 + aoff);
        #pragma unroll
        for (int nt = 0; nt < 6; ++nt) {
            short8 b = w1f[(ks*6+nt)*64 + lane];
            acc[0][nt] = __builtin_amdgcn_mfma_f32_16x16x32_bf16(a0, b, acc[0][nt], 0, 0, 0);
            acc[1][nt] = __builtin_amdgcn_mfma_f32_16x16x32_bf16(a1, b, acc[1][nt], 0, 0, 0);
        }
    }
    __syncthreads();

    short* t1S = stateS;
    #pragma unroll
    for (int i=0;i<2;i++)
      #pragma unroll
      for (int nt=0;nt<6;nt++){
        int f = nt*16 + arow;
        float bb = b1[f];
        #pragma unroll
        for (int r=0;r<4;r++){
            int m = m0 + i*16 + crow + r;
            t1S[m*104 + f] = f2bf(silu_f(acc[i][nt][r] + bb));
        }
      }
    __syncthreads();

    #pragma unroll
    for (int i=0;i<2;i++)
      #pragma unroll
      for (int n=0;n<6;n++) acc[i][n] = fzero;

    const short8* w2f = (const short8*)w2sw;
    #pragma unroll
    for (int ks = 0; ks < 3; ++ks) {
        short8 a0 = *(const short8*)(t1S + (m0+arow)*104    + ks*32 + aoff);
        short8 a1 = *(const short8*)(t1S + (m0+16+arow)*104 + ks*32 + aoff);
        #pragma unroll
        for (int nt = 0; nt < 6; ++nt) {
            short8 b = w2f[(ks*6+nt)*64 + lane];
            acc[0][nt] = __builtin_amdgcn_mfma_f32_16x16x32_bf16(a0, b, acc[0][nt], 0, 0, 0);
            acc[1][nt] = __builtin_amdgcn_mfma_f32_16x16x32_bf16(a1, b, acc[1][nt], 0, 0, 0);
        }
    }

    #pragma unroll
    for (int i=0;i<2;i++)
      #pragma unroll
      for (int nt=0;nt<6;nt++){
        int f = nt*16 + arow;
        float bb = b2[f];
        #pragma unroll
        for (int r=0;r<4;r++){
            int m = m0 + i*16 + crow + r;
            int node = n0 + m;
            if (node < N) {
                size_t idx = (size_t)node*HDIM + f;
                float o = h[idx] + acc[i][nt][r] + bb;
                h[idx]   = o;
                hbf[idx] = f2bf(o);
                aggr[idx] = 0.0f;
            }
        }
      }
}

// ---------------- embed: h = silu([x|pe] W1 + b1) W2 + b2 ----------------
__global__ __launch_bounds__(256,2) void embed_kernel(
    const float* __restrict__ x, const float* __restrict__ pe,
    const short* __restrict__ w1sw, const float* __restrict__ b1,
    const short* __restrict__ w2sw, const float* __restrict__ b2,
    float* __restrict__ h, short* __restrict__ hbf, int N)
{
    __shared__ short stateS[TILE*72];    // K padded to 64, stride 72
    __shared__ short t1S[TILE*104];
    const int t  = threadIdx.x;
    const int n0 = blockIdx.x * TILE;

    if (t < TILE) {
        int node = n0 + t;
        short* row = stateS + t*72;
        if (node < N) {
            #pragma unroll
            for (int j=0;j<11;j++) row[j]    = f2bf(x[(size_t)node*11 + j]);
            #pragma unroll
            for (int j=0;j<24;j++) row[11+j] = f2bf(pe[(size_t)node*24 + j]);
            #pragma unroll
            for (int j=35;j<64;j++) row[j] = 0;
        } else {
            #pragma unroll
            for (int j=0;j<64;j++) row[j] = 0;
        }
    }
    __syncthreads();

    const int lane = t & 63;
    const int wv   = t >> 6;
    const int m0   = wv * 32;
    const int arow = lane & 15;
    const int aq   = lane >> 4;
    const int aoff = aq * 8;
    const int crow = aq * 4;
    const float4v fzero = {0.f,0.f,0.f,0.f};

    float4v acc[2][6];
    #pragma unroll
    for (int i=0;i<2;i++)
      #pragma unroll
      for (int n=0;n<6;n++) acc[i][n] = fzero;

    const short8* w1f = (const short8*)w1sw;
    #pragma unroll
    for (int ks = 0; ks < 2; ++ks) {
        short8 a0 = *(const short8*)(stateS + (m0+arow)*72    + ks*32 + aoff);
        short8 a1 = *(const short8*)(stateS + (m0+16+arow)*72 + ks*32 + aoff);
        #pragma unroll
        for (int nt = 0; nt < 6; ++nt) {
            short8 b = w1f[(ks*6+nt)*64 + lane];
            acc[0][nt] = __builtin_amdgcn_mfma_f32_16x16x32_bf16(a0, b, acc[0][nt], 0, 0, 0);
            acc[1][nt] = __builtin_amdgcn_mfma_f32_16x16x32_bf16(a1, b, acc[1][nt], 0, 0, 0);
        }
    }

    #pragma unroll
    for (int i=0;i<2;i++)
      #pragma unroll
      for (int nt=0;nt<6;nt++){
        int f = nt*16 + arow;
        float bb = b1[f];
        #pragma unroll
        for (int r=0;r<4;r++){
            int m = m0 + i*16 + crow + r;
            t1S[m*104 + f] = f2bf(silu_f(acc[i][nt][r] + bb));
        }
      }
    __syncthreads();

    #pragma unroll
    for (int i=0;i<2;i++)
      #pragma unroll
      for (int n=0;n<6;n++) acc[i][n] = fzero;

    const short8* w2f = (const short8*)w2sw;
    #pragma unroll
    for (int ks = 0; ks < 3; ++ks) {
        short8 a0 = *(const short8*)(t1S + (m0+arow)*104    + ks*32 + aoff);
        short8 a1 = *(const short8*)(t1S + (m0+16+arow)*104 + ks*32 + aoff);
        #pragma unroll
        for (int nt = 0; nt < 6; ++nt) {
            short8 b = w2f[(ks*6+nt)*64 + lane];
            acc[0][nt] = __builtin_amdgcn_mfma_f32_16x16x32_bf16(a0, b, acc[0][nt], 0, 0, 0);
            acc[1][nt] = __builtin_amdgcn_mfma_f32_16x16x32_bf16(a1, b, acc[1][nt], 0, 0, 0);
        }
    }

    #pragma unroll
    for (int i=0;i<2;i++)
      #pragma unroll
      for (int nt=0;nt<6;nt++){
        int f = nt*16 + arow;
        float bb = b2[f];
        #pragma unroll
        for (int r=0;r<4;r++){
            int m = m0 + i*16 + crow + r;
            int node = n0 + m;
            if (node < N) {
                size_t idx = (size_t)node*HDIM + f;
                float o = acc[i][nt][r] + bb;
                h[idx]   = o;
                hbf[idx] = f2bf(o);
            }
        }
      }
}

// ---------------- pre-MLP fused with graph pooling ----------------
__global__ __launch_bounds__(256,2) void prepool_kernel(
    const short* __restrict__ hbf,
    const short* __restrict__ w1sw, const float* __restrict__ b1,
    const short* __restrict__ w2sw, const float* __restrict__ b2,
    const int* __restrict__ batch, float* __restrict__ pooled, int N)
{
    __shared__ short stateS[TILE*104];
    __shared__ short t1S[TILE*104];
    const int t  = threadIdx.x;
    const int n0 = blockIdx.x * TILE;

    #pragma unroll
    for (int it = 0; it < 6; ++it) {
        int q = it*256 + t;    // 128 rows * 12 chunks
        int c = q % 12;
        int i = q / 12;
        int node = n0 + i;
        uint4v v = {0u,0u,0u,0u};
        if (node < N) v = *(const uint4v*)(hbf + (size_t)node*HDIM + c*8);
        *(uint4v*)(stateS + i*104 + c*8) = v;
    }
    __syncthreads();

    const int lane = t & 63;
    const int wv   = t >> 6;
    const int m0   = wv * 32;
    const int arow = lane & 15;
    const int aq   = lane >> 4;
    const int aoff = aq * 8;
    const int crow = aq * 4;
    const float4v fzero = {0.f,0.f,0.f,0.f};

    float4v acc[2][6];
    #pragma unroll
    for (int i=0;i<2;i++)
      #pragma unroll
      for (int n=0;n<6;n++) acc[i][n] = fzero;

    const short8* w1f = (const short8*)w1sw;
    #pragma unroll
    for (int ks = 0; ks < 3; ++ks) {
        short8 a0 = *(const short8*)(stateS + (m0+arow)*104    + ks*32 + aoff);
        short8 a1 = *(const short8*)(stateS + (m0+16+arow)*104 + ks*32 + aoff);
        #pragma unroll
        for (int nt = 0; nt < 6; ++nt) {
            short8 b = w1f[(ks*6+nt)*64 + lane];
            acc[0][nt] = __builtin_amdgcn_mfma_f32_16x16x32_bf16(a0, b, acc[0][nt], 0, 0, 0);
            acc[1][nt] = __builtin_amdgcn_mfma_f32_16x16x32_bf16(a1, b, acc[1][nt], 0, 0, 0);
        }
    }

    #pragma unroll
    for (int i=0;i<2;i++)
      #pragma unroll
      for (int nt=0;nt<6;nt++){
        int f = nt*16 + arow;
        float bb = b1[f];
        #pragma unroll
        for (int r=0;r<4;r++){
            int m = m0 + i*16 + crow + r;
            t1S[m*104 + f] = f2bf(silu_f(acc[i][nt][r] + bb));
        }
      }
    __syncthreads();

    #pragma unroll
    for (int i=0;i<2;i++)
      #pragma unroll
      for (int n=0;n<6;n++) acc[i][n] = fzero;

    const short8* w2f = (const short8*)w2sw;
    #pragma unroll
    for (int ks = 0; ks < 3; ++ks) {
        short8 a0 = *(const short8*)(t1S + (m0+arow)*104    + ks*32 + aoff);
        short8 a1 = *(const short8*)(t1S + (m0+16+arow)*104 + ks*32 + aoff);
        #pragma unroll
        for (int nt = 0; nt < 6; ++nt) {
            short8 b = w2f[(ks*6+nt)*64 + lane];
            acc[0][nt] = __builtin_amdgcn_mfma_f32_16x16x32_bf16(a0, b, acc[0][nt], 0, 0, 0);
            acc[1][nt] = __builtin_amdgcn_mfma_f32_16x16x32_bf16(a1, b, acc[1][nt], 0, 0, 0);
        }
    }

    #pragma unroll
    for (int i=0;i<2;i++)
      #pragma unroll
      for (int nt=0;nt<6;nt++){
        int f = nt*16 + arow;
        float bb = b2[f];
        #pragma unroll
        for (int r=0;r<4;r++){
            int m = m0 + i*16 + crow + r;
            int node = n0 + m;
            if (node < N) {
                float v = acc[i][nt][r] + bb;
                atomicAdd(&pooled[(size_t)batch[node]*HDIM + f], v);
            }
        }
      }
}

// ---------------- readout: out[g] = silu(pooled W1 + b1) W2 + b2 ----------------
__global__ __launch_bounds__(128) void readout_kernel(
    const float* __restrict__ pooled,
    const float* __restrict__ w1, const float* __restrict__ b1,
    const float* __restrict__ w2, const float* __restrict__ b2,
    float* __restrict__ out)
{
    __shared__ float red[128];
    const int g = blockIdx.x;
    const int t = threadIdx.x;
    float p = 0.0f;
    if (t < HDIM) {
        float acc = b1[t];
        for (int k = 0; k < HDIM; ++k)
            acc += pooled[(size_t)g*HDIM + k] * w1[(size_t)k*HDIM + t];
        acc = silu_f(acc);
        p = acc * w2[t];
    }
    red[t] = p;
    __syncthreads();
    for (int s = 64; s > 0; s >>= 1) {
        if (t < s) red[t] += red[t + s];
        __syncthreads();
    }
    if (t == 0) out[g] = red[0] + b2[0];
}

extern "C" void kernel_launch(void* const* d_in, const int* in_sizes, int n_in,
                              void* d_out, int out_size, void* d_ws, size_t ws_size,
                              hipStream_t stream)
{
    const float* x        = (const float*)d_in[0];
    const float* pos      = (const float*)d_in[1];
    const float* pe       = (const float*)d_in[2];
    const int*   ei       = (const int*)d_in[3];
    const int*   batch    = (const int*)d_in[4];
    const float* embed_w1 = (const float*)d_in[5];
    const float* embed_b1 = (const float*)d_in[6];
    const float* embed_w2 = (const float*)d_in[7];
    const float* embed_b2 = (const float*)d_in[8];
    const float* msg_w1   = (const float*)d_in[9];
    const float* msg_b1   = (const float*)d_in[10];
    const float* msg_w2   = (const float*)d_in[11];
    const float* msg_b2   = (const float*)d_in[12];
    const float* upd_w1   = (const float*)d_in[13];
    const float* upd_b1   = (const float*)d_in[14];
    const float* upd_w2   = (const float*)d_in[15];
    const float* upd_b2   = (const float*)d_in[16];
    const float* pre_w1   = (const float*)d_in[17];
    const float* pre_b1   = (const float*)d_in[18];
    const float* pre_w2   = (const float*)d_in[19];
    const float* pre_b2   = (const float*)d_in[20];
    const float* ro_w1    = (const float*)d_in[21];
    const float* ro_b1    = (const float*)d_in[22];
    const float* ro_w2    = (const float*)d_in[23];
    const float* ro_b2    = (const float*)d_in[24];

    const int E = in_sizes[3] / 2;
    const int N = in_sizes[4];
    const int G = out_size;

    char* ws = (char*)d_ws;
    size_t off = 0;
    auto alloc = [&](size_t bytes){ void* p = ws + off; off += (bytes + 255) & ~(size_t)255; return p; };
    float* h      = (float*)alloc((size_t)N*HDIM*4);
    short* hbf    = (short*)alloc((size_t)N*HDIM*2);
    float* aggr   = (float*)alloc((size_t)N*HDIM*4);
    float* pooled = (float*)alloc((size_t)G*HDIM*4);
    short* wsw    = (short*)alloc((size_t)83*3072*2);
    int*   deg    = (int*)alloc((size_t)N*4);
    int*   cur    = (int*)alloc((size_t)N*4);
    int*   send_s = (int*)alloc((size_t)E*4);
    int*   rec_s  = (int*)alloc((size_t)E*4);
    float* dist_s = (float*)alloc((size_t)E*4);

    hipMemsetAsync(aggr,   0, (size_t)N*HDIM*4, stream);
    hipMemsetAsync(pooled, 0, (size_t)G*HDIM*4, stream);
    hipMemsetAsync(deg,    0, (size_t)N*4, stream);

    SwTable T;
    int ck = 0, ji = 0;
    auto add = [&](const float* s, int ks, int ksrc){
        T.j[ji].src = s; T.j[ji].ck = ck; T.j[ji].ks = ks; T.j[ji].ksrc = ksrc;
        ji++; ck += ks;
    };
    add(embed_w1, 2, 35);   // ck 0
    add(embed_w2, 3, 96);   // ck 2
    add(pre_w1,   3, 96);   // ck 5
    add(pre_w2,   3, 96);   // ck 8
    for (int l=0;l<4;l++) add(msg_w1 + (size_t)l*193*96, 6, 192);  // ck 11+6l
    for (int l=0;l<4;l++) add(msg_w2 + (size_t)l*96*96,  3, 96);   // ck 35+3l
    for (int l=0;l<4;l++) add(upd_w1 + (size_t)l*192*96, 6, 192);  // ck 47+6l
    for (int l=0;l<4;l++) add(upd_w2 + (size_t)l*96*96,  3, 96);   // ck 71+3l
    const int total = 83*3072;
    swizzle_kernel<<<(total+255)/256, 256, 0, stream>>>(T, wsw, total);

    // counting sort of edges by rec (+ precompute dist in sorted order)
    const int nbE256 = (E + 255) / 256;
    hist_kernel<<<nbE256, 256, 0, stream>>>(ei + E, deg, E);
    scan_kernel<<<1, 1024, 0, stream>>>(deg, cur, N);
    scatter_kernel<<<nbE256, 256, 0, stream>>>(ei, ei + E, pos, cur, send_s, rec_s, dist_s, E);

    const int nbN = (N + TILE - 1) / TILE;
    embed_kernel<<<nbN, 256, 0, stream>>>(x, pe, wsw + 0, embed_b1, wsw + 2*3072, embed_b2, h, hbf, N);

    const int nbE = (E + TILE - 1) / TILE;
    for (int l = 0; l < 4; ++l) {
        edge_kernel<<<nbE, 256, 0, stream>>>(hbf, send_s, rec_s, dist_s,
            wsw + (11 + 6*l)*3072, msg_w1 + (size_t)l*193*96 + (size_t)192*96, msg_b1 + l*96,
            wsw + (35 + 3*l)*3072, msg_b2 + l*96, aggr, E);
        update_kernel<<<nbN, 256, 0, stream>>>(h, hbf, aggr,
            wsw + (47 + 6*l)*3072, upd_b1 + l*96,
            wsw + (71 + 3*l)*3072, upd_b2 + l*96, N);
    }

    prepool_kernel<<<nbN, 256, 0, stream>>>(hbf, wsw + 5*3072, pre_b1, wsw + 8*3072, pre_b2,
                                            batch, pooled, N);
    readout_kernel<<<G, 128, 0, stream>>>(pooled, ro_w1, ro_b1, ro_w2, ro_b2, (float*)d_out);
}